// Round 10
// baseline (8711.317 us; speedup 1.0000x reference)
//
#include <hip/hip_runtime.h>

// PopulationODE: sequential RK4 scan, T=4096, state=4, HID=32.
// One wave64. Round-10: speculative-parallel RK4 (r8/r9 numerics, proven
// absmax 0.0) with op-group interleaving PINNED by sched_barrier(0).
//
// r9 lesson: source-level interleave is destroyed by the pressure-
// minimizing machine scheduler (VGPR stayed 72 = streams serialized).
// Fix: __builtin_amdgcn_sched_barrier(0) after every op-group makes the
// interleave structural -- each dependent hop in stream w has the other
// streams' ops between it and its producer, hiding VALU/trans latency.

__device__ __forceinline__ float fexp2(float x) { return __builtin_amdgcn_exp2f(x); }
__device__ __forceinline__ float frcp(float x) { return __builtin_amdgcn_rcpf(x); }
#define C_TANH 2.8853900817779268f
#define C_NSIG (-1.4426950408889634f)
#define SB() __builtin_amdgcn_sched_barrier(0)

template<int CTRL>
__device__ __forceinline__ float dppmov(float x) {
  return __int_as_float(__builtin_amdgcn_update_dpp(
      0, __float_as_int(x), CTRL, 0xF, 0xF, true));
}
#define RORc(K) (0x120 | (K))

__device__ __forceinline__ void p16swap(float& a, float& b) {
  asm("s_nop 1\n\tv_permlane16_swap_b32 %0, %1" : "+v"(a), "+v"(b));
}
__device__ __forceinline__ void p32swap(float& a, float& b) {
  asm("s_nop 1\n\tv_permlane32_swap_b32 %0, %1" : "+v"(a), "+v"(b));
}

#define MV8(W, BZ, X, SOUT) do {                                       \
    float b0_ = fmaf((X),             W[0], (BZ));                     \
    float b1_ = dppmov<RORc(1)>(X)  * W[1];                            \
    float b2_ = dppmov<RORc(2)>(X)  * W[2];                            \
    float b3_ = dppmov<RORc(3)>(X)  * W[3];                            \
    float b4_ = dppmov<RORc(4)>(X)  * W[4];                            \
    float b5_ = dppmov<RORc(5)>(X)  * W[5];                            \
    float b6_ = dppmov<RORc(6)>(X)  * W[6];                            \
    float b7_ = dppmov<RORc(7)>(X)  * W[7];                            \
    b0_ = fmaf(dppmov<RORc(8)>(X),  W[8],  b0_);                       \
    b1_ = fmaf(dppmov<RORc(9)>(X),  W[9],  b1_);                       \
    b2_ = fmaf(dppmov<RORc(10)>(X), W[10], b2_);                       \
    b3_ = fmaf(dppmov<RORc(11)>(X), W[11], b3_);                       \
    b4_ = fmaf(dppmov<RORc(12)>(X), W[12], b4_);                       \
    b5_ = fmaf(dppmov<RORc(13)>(X), W[13], b5_);                       \
    b6_ = fmaf(dppmov<RORc(14)>(X), W[14], b6_);                       \
    b7_ = fmaf(dppmov<RORc(15)>(X), W[15], b7_);                       \
    SOUT = ((b0_ + b1_) + (b2_ + b3_)) + ((b4_ + b5_) + (b6_ + b7_));  \
  } while (0)

// One Jacobi sweep over streams WBEG..3. Op-group interleaved, each
// group pinned by sched_barrier(0) so the emitted ISA keeps the
// cross-stream interleave (r9: scheduler re-serialized without this).
#define GROUP(WBEG) do {                                                    \
    float g0[4], u1[4], q2[4], g1[4], g1r[4], u2[4], g2[4], p0[4], p1[4];   \
    _Pragma("unroll") for (int w = WBEG; w < 4; ++w)                        \
      g0[w] = frcp(fexp2(z[w]) + 1.0f);                                     \
    SB();                                                                   \
    _Pragma("unroll") for (int w = WBEG; w < 4; ++w)                        \
      MV8(w1a, bz1a, g0[w], u1[w]);                                         \
    SB();                                                                   \
    _Pragma("unroll") for (int w = WBEG; w < 4; ++w)                        \
      MV8(w2a, 0.0f, g0[w], q2[w]);                                         \
    SB();                                                                   \
    _Pragma("unroll") for (int w = WBEG; w < 4; ++w)                        \
      { float b = u1[w]; p16swap(u1[w], b); u1[w] += b; }                   \
    SB();                                                                   \
    _Pragma("unroll") for (int w = WBEG; w < 4; ++w)                        \
      g1[w] = frcp(fexp2(u1[w]) + 1.0f);                                    \
    SB();                                                                   \
    _Pragma("unroll") for (int w = WBEG; w < 4; ++w)                        \
      { float b = q2[w]; p16swap(q2[w], b); q2[w] += b; }                   \
    SB();                                                                   \
    _Pragma("unroll") for (int w = WBEG; w < 4; ++w) {                      \
      float seed = (seedsel ? q2[w] : 0.0f) + c2sel;                        \
      MV8(m21, seed, g1[w], u2[w]);                                         \
    }                                                                       \
    SB();                                                                   \
    _Pragma("unroll") for (int w = WBEG; w < 4; ++w)                        \
      g1r[w] = relayout(g1[w]);                                             \
    SB();                                                                   \
    _Pragma("unroll") for (int w = WBEG; w < 4; ++w)                        \
      { float b = u2[w]; p32swap(u2[w], b); u2[w] += b; }                   \
    SB();                                                                   \
    _Pragma("unroll") for (int w = WBEG; w < 4; ++w)                        \
      g2[w] = frcp(fexp2(u2[w]) + 1.0f);                                    \
    SB();                                                                   \
    _Pragma("unroll") for (int w = WBEG; w < 4; ++w) {                      \
      p0[w] = fmaf(wo2a, g2[w], fmaf(wo1a, g1r[w], fmaf(woXa, g0[w], boa)));\
      p1[w] = fmaf(wo2b, g2[w], fmaf(wo1b, g1r[w], fmaf(woXb, g0[w], bob)));\
    }                                                                       \
    SB();                                                                   \
    _Pragma("unroll") for (int w = WBEG; w < 4; ++w)                        \
      { p0[w] += dppmov<RORc(8)>(p0[w]); p1[w] += dppmov<RORc(8)>(p1[w]); } \
    SB();                                                                   \
    _Pragma("unroll") for (int w = WBEG; w < 4; ++w)                        \
      { p0[w] += dppmov<RORc(4)>(p0[w]); p1[w] += dppmov<RORc(4)>(p1[w]); } \
    SB();                                                                   \
    _Pragma("unroll") for (int w = WBEG; w < 4; ++w)                        \
      { p0[w] += dppmov<RORc(2)>(p0[w]); p1[w] += dppmov<RORc(2)>(p1[w]); } \
    SB();                                                                   \
    _Pragma("unroll") for (int w = WBEG; w < 4; ++w)                        \
      { p0[w] += dppmov<RORc(1)>(p0[w]); p1[w] += dppmov<RORc(1)>(p1[w]); } \
    SB();                                                                   \
    _Pragma("unroll") for (int w = WBEG; w < 4; ++w) {                      \
      float q = p0[w]; p16swap(p0[w], q); p0[w] += q;                       \
      float r = p1[w]; p16swap(p1[w], r); p1[w] += r;                       \
    }                                                                       \
    SB();                                                                   \
    _Pragma("unroll") for (int w = WBEG; w < 4; ++w) {                      \
      na[w] = frcp(1.0f + fexp2(p0[w]));                                    \
      nb[w] = frcp(1.0f + fexp2(p1[w]));                                    \
    }                                                                       \
    SB();                                                                   \
    _Pragma("unroll") for (int w = WBEG; w < 4; ++w) {                      \
      float gp = fmaf(wpb[w], nb[w], wpa[w] * na[w]);                       \
      float gq = gp;                                                        \
      p32swap(gp, gq);                                                      \
      gkv[w] = gp + gq;                                                     \
    }                                                                       \
    SB();                                                                   \
  } while (0)

__global__ __launch_bounds__(64, 1) __attribute__((amdgpu_waves_per_eu(1, 1)))
void ode_kernel(const float* __restrict__ s_grid,
                const float* __restrict__ y0in,
                const float* __restrict__ Win,
                const float* __restrict__ bin_,
                const float* __restrict__ W1a, const float* __restrict__ b1a,
                const float* __restrict__ W1b, const float* __restrict__ b1b,
                const float* __restrict__ W2a, const float* __restrict__ b2a,
                const float* __restrict__ W2b, const float* __restrict__ b2b,
                const float* __restrict__ Wout, const float* __restrict__ bout,
                const float* __restrict__ Aarr,
                float* __restrict__ out, int T) {
  const int lane = threadIdx.x;
  const int i = lane & 15;
  const int m = lane >> 4;
  const int mlo = m & 1;
  const int mhi = m >> 1;

  // ---- stage s_grid into LDS ----
  __shared__ float s_lds[4096];
  for (int idx = lane; idx < T && idx < 4096; idx += 64)
    s_lds[idx] = s_grid[idx];
  __syncthreads();

  // ---- direction probes ----
  int delta;
  {
    float pr = (float)i;
    float pr1 = dppmov<RORc(1)>(pr);
    delta = (((int)pr1) - i) & 15;
  }
  bool p32_c_low;
  {
    float v = (float)(lane >> 5);
    float c = v, d = v;
    p32swap(c, d);
    p32_c_low = (c == 0.0f);
  }

  // ---- weight prep (one-time, identical to rounds 7-9) ----
  const int rA = 16 * mhi + i, hA = mlo;
  const int rB = 16 * mlo + i, hB = mhi;
  const int r_in = 16 * mlo + i;
  const int e1 = r_in;

  float w1a[16], w2a[16], m21[16];
#pragma unroll 1
  for (int k = 0; k < 16; ++k) {
    int cA = hA * 16 + ((i + delta * k) & 15);
    int cB = hB * 16 + ((i + delta * k) & 15);
    w1a[k] = W1a[rA * 32 + cA] * (-2.0f * C_TANH);
    w2a[k] = W2a[rA * 32 + cA] * (-2.0f * C_TANH);
    float acc = 0.0f;
    for (int q = 0; q < 32; ++q)
      acc = fmaf(W2a[rB * 32 + q], W1b[q * 32 + cB], acc);
    m21[k] = acc * (-2.0f * C_TANH);
  }
  float bz1a;
  {
    float rs = 0.0f;
    for (int c = 0; c < 32; ++c) rs += W1a[rA * 32 + c];
    bz1a = hA ? 0.0f : C_TANH * (b1a[rA] + rs);
  }
  float c2sel;
  {
    float rs2a = 0.0f, m21rs = 0.0f, wb = 0.0f;
    for (int q = 0; q < 32; ++q) {
      float w2q = W2a[rB * 32 + q];
      rs2a += w2q;
      float rs1bq = 0.0f;
      for (int c = 0; c < 32; ++c) rs1bq += W1b[q * 32 + c];
      m21rs = fmaf(w2q, rs1bq, m21rs);
      wb = fmaf(w2q, b1b[q], wb);
    }
    c2sel = hB ? 0.0f : C_TANH * (rs2a + m21rs + wb + b2a[rB]);
  }
  const bool seedsel = (mlo == mhi);

  float winy0 = Win[r_in * 5 + 0] * C_TANH;
  float winy1 = Win[r_in * 5 + 1] * C_TANH;
  float winy2 = Win[r_in * 5 + 2] * C_TANH;
  float winy3 = Win[r_in * 5 + 3] * C_TANH;
  float wins  = Win[r_in * 5 + 4] * C_TANH;
  float binr  = bin_[r_in] * C_TANH;
  float gsel_a = mhi ? winy2 : winy0;
  float gsel_b = mhi ? winy3 : winy1;

  const int ra_ = 2 * mhi, rb_ = 2 * mhi + 1;
  float woXa = Wout[ra_ * 32 + e1] * (-2.0f * C_NSIG);
  float woXb = Wout[rb_ * 32 + e1] * (-2.0f * C_NSIG);
  float wo1a, wo1b, wo2a, wo2b, boa, bob;
  {
    float w1s_a = 0.0f, w1s_b = 0.0f, w2s_a = 0.0f, w2s_b = 0.0f;
    float rsX_a = 0.0f, rsX_b = 0.0f, rs1_a = 0.0f, rs1_b = 0.0f;
    float rs2_a = 0.0f, rs2_b = 0.0f, bt_a = 0.0f, bt_b = 0.0f;
    for (int q = 0; q < 32; ++q) {
      float waq = Wout[ra_ * 32 + q], wbq = Wout[rb_ * 32 + q];
      w1s_a = fmaf(waq, W1b[q * 32 + e1], w1s_a);
      w1s_b = fmaf(wbq, W1b[q * 32 + e1], w1s_b);
      w2s_a = fmaf(waq, W2b[q * 32 + e1], w2s_a);
      w2s_b = fmaf(wbq, W2b[q * 32 + e1], w2s_b);
      rsX_a += waq; rsX_b += wbq;
      float rs1bq = 0.0f, rs2bq = 0.0f;
      for (int c = 0; c < 32; ++c) {
        rs1bq += W1b[q * 32 + c];
        rs2bq += W2b[q * 32 + c];
      }
      rs1_a = fmaf(waq, rs1bq, rs1_a); rs1_b = fmaf(wbq, rs1bq, rs1_b);
      rs2_a = fmaf(waq, rs2bq, rs2_a); rs2_b = fmaf(wbq, rs2bq, rs2_b);
      float bs = b1b[q] + b2b[q];
      bt_a = fmaf(waq, bs, bt_a); bt_b = fmaf(wbq, bs, bt_b);
    }
    wo1a = w1s_a * (-2.0f * C_NSIG); wo1b = w1s_b * (-2.0f * C_NSIG);
    wo2a = w2s_a * (-2.0f * C_NSIG); wo2b = w2s_b * (-2.0f * C_NSIG);
    boa = (bout[ra_] + bt_a + rsX_a + rs1_a + rs2_a) * (C_NSIG / 32.0f);
    bob = (bout[rb_] + bt_b + rsX_b + rs1_b + rs2_b) * (C_NSIG / 32.0f);
  }
  float Aa = mhi ? Aarr[2] : Aarr[0];
  float Ab = mhi ? Aarr[3] : Aarr[1];

  auto relayout = [&](float v) -> float {
    float c = v, d = v;
    p32swap(c, d);
    float lo = p32_c_low ? c : d;
    float hi = p32_c_low ? d : c;
    return mlo ? hi : lo;
  };

  // ---- per-step stream state ----
  float z[4], na[4], nb[4], gkv[4];
  float pfa[4], pfb[4], wpa[4], wpb[4];

  auto setpref = [&](float yA, float yB, int w) {
    float sa = frcp(1.0f + fexp2(yA * C_NSIG));
    float sb = frcp(1.0f + fexp2(yB * C_NSIG));
    pfa[w] = 0.01f * sa * (Aa - sa);
    pfb[w] = 0.01f * sb * (Ab - sb);
    wpa[w] = gsel_a * pfa[w];
    wpb[w] = gsel_b * pfb[w];
  };

  // ---- state ----
  float y00 = y0in[0], y01 = y0in[1], y02 = y0in[2], y03 = y0in[3];
  float ya = mhi ? y02 : y00;
  float yb = mhi ? y03 : y01;

  if ((lane & 0x1E) == 0)
    out[(lane >> 4) + (lane & 1)] = (lane & 1) ? yb : ya;

  float sp = s_lds[0];
  float sn = (T > 1) ? s_lds[1] : sp;

  float zb = fmaf(winy0, y00, fmaf(winy1, y01, fmaf(winy2, y02,
             fmaf(winy3, y03, fmaf(wins, sp, binr)))));

  // carried guesses (prev-step finals); zero-init safe (r8/r9: absmax 0.0)
  float gkc0 = 0.0f, gkc1 = 0.0f, gkc2 = 0.0f;
  float Kca0 = 0.0f, Kca1 = 0.0f, Kca2 = 0.0f;
  float Kcb0 = 0.0f, Kcb1 = 0.0f, Kcb2 = 0.0f;

  for (int t = 0; t < T - 1; ++t) {
    int tn = (t + 2 < T) ? (t + 2) : (T - 1);
    float snn = s_lds[tn < 4096 ? tn : 4095];
    float h = sn - sp;
    float hh = 0.5f * h;
    float h6 = h * (1.0f / 6.0f);
    float zbw = fmaf(wins, h, zb);

    // ---- iter 1: all 4 stages, speculative inputs from guesses ----
    z[0] = zb;
    z[1] = fmaf(hh, gkc0, zb);
    z[2] = fmaf(hh, gkc1, zb);
    z[3] = fmaf(h,  gkc2, zb);
    setpref(ya, yb, 0);
    setpref(fmaf(hh, Kca0, ya), fmaf(hh, Kcb0, yb), 1);
    setpref(fmaf(hh, Kca1, ya), fmaf(hh, Kcb1, yb), 2);
    setpref(fmaf(h,  Kca2, ya), fmaf(h,  Kcb2, yb), 3);
    GROUP(0);
    float Ka[4], Kb[4];
#pragma unroll
    for (int w = 0; w < 4; ++w) {
      Ka[w] = pfa[w] * na[w];
      Kb[w] = pfb[w] * nb[w];
    }

    // ---- iter 2: stages 2-4 with iter-1 outputs (k1,k2 -> exact) ----
    z[1] = fmaf(hh, gkv[0], zb);
    z[2] = fmaf(hh, gkv[1], zb);
    z[3] = fmaf(h,  gkv[2], zb);
    setpref(fmaf(hh, Ka[0], ya), fmaf(hh, Kb[0], yb), 1);
    setpref(fmaf(hh, Ka[1], ya), fmaf(hh, Kb[1], yb), 2);
    setpref(fmaf(h,  Ka[2], ya), fmaf(h,  Kb[2], yb), 3);
    GROUP(1);
#pragma unroll
    for (int w = 1; w < 4; ++w) {
      Ka[w] = pfa[w] * na[w];
      Kb[w] = pfb[w] * nb[w];
    }

    // ---- combine & update ----
    float aa = Ka[0] + Ka[3] + 2.0f * (Ka[1] + Ka[2]);
    float ab = Kb[0] + Kb[3] + 2.0f * (Kb[1] + Kb[2]);
    float ag = gkv[0] + gkv[3] + 2.0f * (gkv[1] + gkv[2]);
    zb = fmaf(h6, ag, zbw);
    ya = fmaf(h6, aa, ya);
    yb = fmaf(h6, ab, yb);

    // carry guesses for next step
    gkc0 = gkv[0]; gkc1 = gkv[1]; gkc2 = gkv[2];
    Kca0 = Ka[0]; Kca1 = Ka[1]; Kca2 = Ka[2];
    Kcb0 = Kb[0]; Kcb1 = Kb[1]; Kcb2 = Kb[2];

    if ((lane & 0x1E) == 0)
      out[(size_t)(t + 1) * 4 + (lane >> 4) + (lane & 1)] = (lane & 1) ? yb : ya;

    sp = sn;
    sn = snn;
  }
}

extern "C" void kernel_launch(void* const* d_in, const int* in_sizes, int n_in,
                              void* d_out, int out_size, void* d_ws, size_t ws_size,
                              hipStream_t stream) {
  const float* s_grid = (const float*)d_in[0];
  const float* y0 = (const float*)d_in[1];
  const float* Win = (const float*)d_in[2];
  const float* bin_ = (const float*)d_in[3];
  const float* W1a = (const float*)d_in[4];
  const float* b1a = (const float*)d_in[5];
  const float* W1b = (const float*)d_in[6];
  const float* b1b = (const float*)d_in[7];
  const float* W2a = (const float*)d_in[8];
  const float* b2a = (const float*)d_in[9];
  const float* W2b = (const float*)d_in[10];
  const float* b2b = (const float*)d_in[11];
  const float* Wout = (const float*)d_in[12];
  const float* bout = (const float*)d_in[13];
  const float* A = (const float*)d_in[14];
  int T = in_sizes[0];

  ode_kernel<<<1, 64, 0, stream>>>(s_grid, y0, Win, bin_, W1a, b1a, W1b, b1b,
                                   W2a, b2a, W2b, b2b, Wout, bout, A,
                                   (float*)d_out, T);
}

// Round 11
// 4433.631 us; speedup vs baseline: 1.9648x; 1.9648x over previous
//
#include <hip/hip_runtime.h>

// PopulationODE: sequential RK4 scan, T=4096, state=4, HID=32.
// Round-11: speculative-parallel RK4 across 4 WAVES (TLP, not ILP).
//   r8-r10 lesson: the compiler re-serializes in-wave independent
//   streams (VGPR stuck at 72). Hardware TLP: 4 waves on the 4 SIMDs
//   of one CU run truly concurrently.
//   wave w = RK stage w.  Sweep1: all waves eval (guesses from prev
//   step; k1 exact). LDS exchange + barrier. Sweep2: waves 1-3 re-eval
//   with sweep1 inputs (k2 exact; k3,k4 err ~1e-7 -- r8 proved
//   absmax 0.0). Separate iter1/iter2 buffers avoid WAR races.
// Per-stage math identical to r7/r8 (g-form collapsed network).

__device__ __forceinline__ float fexp2(float x) { return __builtin_amdgcn_exp2f(x); }
__device__ __forceinline__ float frcp(float x) { return __builtin_amdgcn_rcpf(x); }
#define C_TANH 2.8853900817779268f
#define C_NSIG (-1.4426950408889634f)

template<int CTRL>
__device__ __forceinline__ float dppmov(float x) {
  return __int_as_float(__builtin_amdgcn_update_dpp(
      0, __float_as_int(x), CTRL, 0xF, 0xF, true));
}
#define RORc(K) (0x120 | (K))

__device__ __forceinline__ void p16swap(float& a, float& b) {
  asm("s_nop 1\n\tv_permlane16_swap_b32 %0, %1" : "+v"(a), "+v"(b));
}
__device__ __forceinline__ void p32swap(float& a, float& b) {
  asm("s_nop 1\n\tv_permlane32_swap_b32 %0, %1" : "+v"(a), "+v"(b));
}

#define MV8(W, BZ, X, SOUT) do {                                       \
    float b0_ = fmaf((X),             W[0], (BZ));                     \
    float b1_ = dppmov<RORc(1)>(X)  * W[1];                            \
    float b2_ = dppmov<RORc(2)>(X)  * W[2];                            \
    float b3_ = dppmov<RORc(3)>(X)  * W[3];                            \
    float b4_ = dppmov<RORc(4)>(X)  * W[4];                            \
    float b5_ = dppmov<RORc(5)>(X)  * W[5];                            \
    float b6_ = dppmov<RORc(6)>(X)  * W[6];                            \
    float b7_ = dppmov<RORc(7)>(X)  * W[7];                            \
    b0_ = fmaf(dppmov<RORc(8)>(X),  W[8],  b0_);                       \
    b1_ = fmaf(dppmov<RORc(9)>(X),  W[9],  b1_);                       \
    b2_ = fmaf(dppmov<RORc(10)>(X), W[10], b2_);                       \
    b3_ = fmaf(dppmov<RORc(11)>(X), W[11], b3_);                       \
    b4_ = fmaf(dppmov<RORc(12)>(X), W[12], b4_);                       \
    b5_ = fmaf(dppmov<RORc(13)>(X), W[13], b5_);                       \
    b6_ = fmaf(dppmov<RORc(14)>(X), W[14], b6_);                       \
    b7_ = fmaf(dppmov<RORc(15)>(X), W[15], b7_);                       \
    SOUT = ((b0_ + b1_) + (b2_ + b3_)) + ((b4_ + b5_) + (b6_ + b7_));  \
  } while (0)

__global__ __launch_bounds__(256, 1) __attribute__((amdgpu_waves_per_eu(1, 1)))
void ode_kernel(const float* __restrict__ s_grid,
                const float* __restrict__ y0in,
                const float* __restrict__ Win,
                const float* __restrict__ bin_,
                const float* __restrict__ W1a, const float* __restrict__ b1a,
                const float* __restrict__ W1b, const float* __restrict__ b1b,
                const float* __restrict__ W2a, const float* __restrict__ b2a,
                const float* __restrict__ W2b, const float* __restrict__ b2b,
                const float* __restrict__ Wout, const float* __restrict__ bout,
                const float* __restrict__ Aarr,
                float* __restrict__ out, int T) {
  const int tid = threadIdx.x;
  const int wave = tid >> 6;      // 0..3 = RK stage owned
  const int lane = tid & 63;
  const int i = lane & 15;
  const int m = lane >> 4;
  const int mlo = m & 1;
  const int mhi = m >> 1;

  // ---- LDS: s_grid stage + iter1/iter2 exchange buffers ----
  __shared__ float s_lds[4096];
  __shared__ float L1g[4][64], L1a[4][64], L1b[4][64];   // sweep-1 outputs
  __shared__ float L2g[4][64], L2a[4][64], L2b[4][64];   // sweep-2 outputs
  for (int idx = tid; idx < T && idx < 4096; idx += 256)
    s_lds[idx] = s_grid[idx];
  __syncthreads();

  // ---- direction probes ----
  int delta;
  {
    float pr = (float)i;
    float pr1 = dppmov<RORc(1)>(pr);
    delta = (((int)pr1) - i) & 15;
  }
  bool p32_c_low;
  {
    float v = (float)(lane >> 5);
    float c = v, d = v;
    p32swap(c, d);
    p32_c_low = (c == 0.0f);
  }

  // ---- weight prep (one-time, identical to r7-r10; per-lane) ----
  const int rA = 16 * mhi + i, hA = mlo;
  const int rB = 16 * mlo + i, hB = mhi;
  const int r_in = 16 * mlo + i;
  const int e1 = r_in;

  float w1a[16], w2a[16], m21[16];
#pragma unroll 1
  for (int k = 0; k < 16; ++k) {
    int cA = hA * 16 + ((i + delta * k) & 15);
    int cB = hB * 16 + ((i + delta * k) & 15);
    w1a[k] = W1a[rA * 32 + cA] * (-2.0f * C_TANH);
    w2a[k] = W2a[rA * 32 + cA] * (-2.0f * C_TANH);
    float acc = 0.0f;
    for (int q = 0; q < 32; ++q)
      acc = fmaf(W2a[rB * 32 + q], W1b[q * 32 + cB], acc);
    m21[k] = acc * (-2.0f * C_TANH);
  }
  float bz1a;
  {
    float rs = 0.0f;
    for (int c = 0; c < 32; ++c) rs += W1a[rA * 32 + c];
    bz1a = hA ? 0.0f : C_TANH * (b1a[rA] + rs);
  }
  float c2sel;
  {
    float rs2a = 0.0f, m21rs = 0.0f, wb = 0.0f;
    for (int q = 0; q < 32; ++q) {
      float w2q = W2a[rB * 32 + q];
      rs2a += w2q;
      float rs1bq = 0.0f;
      for (int c = 0; c < 32; ++c) rs1bq += W1b[q * 32 + c];
      m21rs = fmaf(w2q, rs1bq, m21rs);
      wb = fmaf(w2q, b1b[q], wb);
    }
    c2sel = hB ? 0.0f : C_TANH * (rs2a + m21rs + wb + b2a[rB]);
  }
  const bool seedsel = (mlo == mhi);

  float winy0 = Win[r_in * 5 + 0] * C_TANH;
  float winy1 = Win[r_in * 5 + 1] * C_TANH;
  float winy2 = Win[r_in * 5 + 2] * C_TANH;
  float winy3 = Win[r_in * 5 + 3] * C_TANH;
  float wins  = Win[r_in * 5 + 4] * C_TANH;
  float binr  = bin_[r_in] * C_TANH;
  float gsel_a = mhi ? winy2 : winy0;
  float gsel_b = mhi ? winy3 : winy1;

  const int ra_ = 2 * mhi, rb_ = 2 * mhi + 1;
  float woXa = Wout[ra_ * 32 + e1] * (-2.0f * C_NSIG);
  float woXb = Wout[rb_ * 32 + e1] * (-2.0f * C_NSIG);
  float wo1a, wo1b, wo2a, wo2b, boa, bob;
  {
    float w1s_a = 0.0f, w1s_b = 0.0f, w2s_a = 0.0f, w2s_b = 0.0f;
    float rsX_a = 0.0f, rsX_b = 0.0f, rs1_a = 0.0f, rs1_b = 0.0f;
    float rs2_a = 0.0f, rs2_b = 0.0f, bt_a = 0.0f, bt_b = 0.0f;
    for (int q = 0; q < 32; ++q) {
      float waq = Wout[ra_ * 32 + q], wbq = Wout[rb_ * 32 + q];
      w1s_a = fmaf(waq, W1b[q * 32 + e1], w1s_a);
      w1s_b = fmaf(wbq, W1b[q * 32 + e1], w1s_b);
      w2s_a = fmaf(waq, W2b[q * 32 + e1], w2s_a);
      w2s_b = fmaf(wbq, W2b[q * 32 + e1], w2s_b);
      rsX_a += waq; rsX_b += wbq;
      float rs1bq = 0.0f, rs2bq = 0.0f;
      for (int c = 0; c < 32; ++c) {
        rs1bq += W1b[q * 32 + c];
        rs2bq += W2b[q * 32 + c];
      }
      rs1_a = fmaf(waq, rs1bq, rs1_a); rs1_b = fmaf(wbq, rs1bq, rs1_b);
      rs2_a = fmaf(waq, rs2bq, rs2_a); rs2_b = fmaf(wbq, rs2bq, rs2_b);
      float bs = b1b[q] + b2b[q];
      bt_a = fmaf(waq, bs, bt_a); bt_b = fmaf(wbq, bs, bt_b);
    }
    wo1a = w1s_a * (-2.0f * C_NSIG); wo1b = w1s_b * (-2.0f * C_NSIG);
    wo2a = w2s_a * (-2.0f * C_NSIG); wo2b = w2s_b * (-2.0f * C_NSIG);
    boa = (bout[ra_] + bt_a + rsX_a + rs1_a + rs2_a) * (C_NSIG / 32.0f);
    bob = (bout[rb_] + bt_b + rsX_b + rs1_b + rs2_b) * (C_NSIG / 32.0f);
  }
  float Aa = mhi ? Aarr[2] : Aarr[0];
  float Ab = mhi ? Aarr[3] : Aarr[1];

  auto relayout = [&](float v) -> float {
    float c = v, d = v;
    p32swap(c, d);
    float lo = p32_c_low ? c : d;
    float hi = p32_c_low ? d : c;
    return mlo ? hi : lo;
  };

  // ---- per-wave single-stream stage state ----
  float pfa, pfb, wpa, wpb, na, nb, gkv;

  auto setpref = [&](float yA, float yB) {
    float sa = frcp(1.0f + fexp2(yA * C_NSIG));
    float sb = frcp(1.0f + fexp2(yB * C_NSIG));
    pfa = 0.01f * sa * (Aa - sa);
    pfb = 0.01f * sb * (Ab - sb);
    wpa = gsel_a * pfa;
    wpb = gsel_b * pfb;
  };

  // stage body: r7/r8 verbatim math
  auto STAGE = [&](float zin) {
    float g0v = frcp(fexp2(zin) + 1.0f);                   // ABAB
    float u1; MV8(w1a, bz1a, g0v, u1);
    { float b = u1; p16swap(u1, b); u1 += b; }             // AABB
    float q2; MV8(w2a, 0.0f, g0v, q2);
    { float b = q2; p16swap(q2, b); q2 += b; }             // AABB
    float g1 = frcp(fexp2(u1) + 1.0f);
    float g1r = relayout(g1);
    float seed = (seedsel ? q2 : 0.0f) + c2sel;
    float u2; MV8(m21, seed, g1, u2);
    { float b = u2; p32swap(u2, b); u2 += b; }             // ABAB
    float g2 = frcp(fexp2(u2) + 1.0f);
    float ph0 = fmaf(wo1a, g1r, fmaf(woXa, g0v, boa));
    float ph1 = fmaf(wo1b, g1r, fmaf(woXb, g0v, bob));
    float p0 = fmaf(wo2a, g2, ph0);
    float p1 = fmaf(wo2b, g2, ph1);
    p0 += dppmov<RORc(8)>(p0); p1 += dppmov<RORc(8)>(p1);
    p0 += dppmov<RORc(4)>(p0); p1 += dppmov<RORc(4)>(p1);
    p0 += dppmov<RORc(2)>(p0); p1 += dppmov<RORc(2)>(p1);
    p0 += dppmov<RORc(1)>(p0); p1 += dppmov<RORc(1)>(p1);
    { float q = p0; p16swap(p0, q); p0 += q; }
    { float q = p1; p16swap(p1, q); p1 += q; }
    na = frcp(1.0f + fexp2(p0));
    nb = frcp(1.0f + fexp2(p1));
    float gp = fmaf(wpb, nb, wpa * na);
    float gq = gp;
    p32swap(gp, gq);
    gkv = gp + gq;
  };

  // ---- state (every wave tracks identically) ----
  float y00 = y0in[0], y01 = y0in[1], y02 = y0in[2], y03 = y0in[3];
  float ya = mhi ? y02 : y00;
  float yb = mhi ? y03 : y01;

  if (wave == 0 && (lane & 0x1E) == 0)
    out[(lane >> 4) + (lane & 1)] = (lane & 1) ? yb : ya;

  float sp = s_lds[0];
  float sn = (T > 1) ? s_lds[1] : sp;

  float zb = fmaf(winy0, y00, fmaf(winy1, y01, fmaf(winy2, y02,
             fmaf(winy3, y03, fmaf(wins, sp, binr)))));

  // next-step guesses for this wave's stage (prev-step finals); zero-init
  // safe (r8: absmax 0.0). Wave 0 never uses them (its cw*gkg term = 0*0).
  float gkg = 0.0f, Kag = 0.0f, Kbg = 0.0f;

  for (int t = 0; t < T - 1; ++t) {
    int tn = (t + 2 < T) ? (t + 2) : (T - 1);
    float snn = s_lds[tn < 4096 ? tn : 4095];
    float h = sn - sp;
    float hh = 0.5f * h;
    float h6 = h * (1.0f / 6.0f);
    float zbw = fmaf(wins, h, zb);
    // stage input coefficient: stage0:0, stage1:hh, stage2:hh, stage3:h
    float cw = (wave == 0) ? 0.0f : (wave == 3) ? h : hh;

    // ---- sweep 1: all 4 waves eval their stage with guesses ----
    setpref(fmaf(cw, Kag, ya), fmaf(cw, Kbg, yb));
    STAGE(fmaf(cw, gkg, zb));
    float Ka = pfa * na, Kb = pfb * nb;
    L1g[wave][lane] = gkv;
    L1a[wave][lane] = Ka;
    L1b[wave][lane] = Kb;
    __syncthreads();

    // ---- sweep 2: waves 1-3 re-eval with sweep-1 inputs ----
    if (wave) {
      float gkp = L1g[wave - 1][lane];
      float Kap = L1a[wave - 1][lane];
      float Kbp = L1b[wave - 1][lane];
      setpref(fmaf(cw, Kap, ya), fmaf(cw, Kbp, yb));
      STAGE(fmaf(cw, gkp, zb));
      Ka = pfa * na; Kb = pfb * nb;
      L2g[wave][lane] = gkv;
      L2a[wave][lane] = Ka;
      L2b[wave][lane] = Kb;
    }
    __syncthreads();

    // ---- combine (redundant in every wave): k1 from iter1, k2-4 iter2 ----
    float g0 = L1g[0][lane], g1 = L2g[1][lane];
    float g2 = L2g[2][lane], g3 = L2g[3][lane];
    float Ka0 = L1a[0][lane], Ka1 = L2a[1][lane];
    float Ka2 = L2a[2][lane], Ka3 = L2a[3][lane];
    float Kb0 = L1b[0][lane], Kb1 = L2b[1][lane];
    float Kb2 = L2b[2][lane], Kb3 = L2b[3][lane];

    // next-step guesses: stage w uses final outputs of stage w-1
    if (wave == 1)      { gkg = g0; Kag = Ka0; Kbg = Kb0; }
    else if (wave == 2) { gkg = g1; Kag = Ka1; Kbg = Kb1; }
    else if (wave == 3) { gkg = g2; Kag = Ka2; Kbg = Kb2; }

    float aa = Ka0 + Ka3 + 2.0f * (Ka1 + Ka2);
    float ab = Kb0 + Kb3 + 2.0f * (Kb1 + Kb2);
    float ag = g0 + g3 + 2.0f * (g1 + g2);
    zb = fmaf(h6, ag, zbw);
    ya = fmaf(h6, aa, ya);
    yb = fmaf(h6, ab, yb);

    if (wave == 0 && (lane & 0x1E) == 0)
      out[(size_t)(t + 1) * 4 + (lane >> 4) + (lane & 1)] = (lane & 1) ? yb : ya;

    __syncthreads();   // protect L1/L2 from next step's overwrites

    sp = sn;
    sn = snn;
  }
}

extern "C" void kernel_launch(void* const* d_in, const int* in_sizes, int n_in,
                              void* d_out, int out_size, void* d_ws, size_t ws_size,
                              hipStream_t stream) {
  const float* s_grid = (const float*)d_in[0];
  const float* y0 = (const float*)d_in[1];
  const float* Win = (const float*)d_in[2];
  const float* bin_ = (const float*)d_in[3];
  const float* W1a = (const float*)d_in[4];
  const float* b1a = (const float*)d_in[5];
  const float* W1b = (const float*)d_in[6];
  const float* b1b = (const float*)d_in[7];
  const float* W2a = (const float*)d_in[8];
  const float* b2a = (const float*)d_in[9];
  const float* W2b = (const float*)d_in[10];
  const float* b2b = (const float*)d_in[11];
  const float* Wout = (const float*)d_in[12];
  const float* bout = (const float*)d_in[13];
  const float* A = (const float*)d_in[14];
  int T = in_sizes[0];

  ode_kernel<<<1, 256, 0, stream>>>(s_grid, y0, Win, bin_, W1a, b1a, W1b, b1b,
                                    W2a, b2a, W2b, b2b, Wout, bout, A,
                                    (float*)d_out, T);
}

// Round 12
// 4203.196 us; speedup vs baseline: 2.0725x; 1.0548x over previous
//
#include <hip/hip_runtime.h>

// PopulationODE: sequential RK4 scan, T=4096, state=4, HID=32.
// Round-12: PIPELINED predictor/corrector across 8 waves.
//   waves 0-3: CORRECT step t's stages (exact y(t), P(t) stage inputs)
//   waves 4-7: PREDICT step t+1's stages (y(t+1) guessed from RK4-combine
//              of P(t); zero-order stage-input guesses) -- CONCURRENT.
//   1 eval-latency + 1 barrier per step (double-buffered LDS exchange).
// Numerics: r8/r11 lineage (both absmax 0.0). Guess quality here is
// strictly better than r8's zero-order carry. Stage math is r7 verbatim.

__device__ __forceinline__ float fexp2(float x) { return __builtin_amdgcn_exp2f(x); }
__device__ __forceinline__ float frcp(float x) { return __builtin_amdgcn_rcpf(x); }
#define C_TANH 2.8853900817779268f
#define C_NSIG (-1.4426950408889634f)

template<int CTRL>
__device__ __forceinline__ float dppmov(float x) {
  return __int_as_float(__builtin_amdgcn_update_dpp(
      0, __float_as_int(x), CTRL, 0xF, 0xF, true));
}
#define RORc(K) (0x120 | (K))

__device__ __forceinline__ void p16swap(float& a, float& b) {
  asm("s_nop 1\n\tv_permlane16_swap_b32 %0, %1" : "+v"(a), "+v"(b));
}
__device__ __forceinline__ void p32swap(float& a, float& b) {
  asm("s_nop 1\n\tv_permlane32_swap_b32 %0, %1" : "+v"(a), "+v"(b));
}

#define MV8(W, BZ, X, SOUT) do {                                       \
    float b0_ = fmaf((X),             W[0], (BZ));                     \
    float b1_ = dppmov<RORc(1)>(X)  * W[1];                            \
    float b2_ = dppmov<RORc(2)>(X)  * W[2];                            \
    float b3_ = dppmov<RORc(3)>(X)  * W[3];                            \
    float b4_ = dppmov<RORc(4)>(X)  * W[4];                            \
    float b5_ = dppmov<RORc(5)>(X)  * W[5];                            \
    float b6_ = dppmov<RORc(6)>(X)  * W[6];                            \
    float b7_ = dppmov<RORc(7)>(X)  * W[7];                            \
    b0_ = fmaf(dppmov<RORc(8)>(X),  W[8],  b0_);                       \
    b1_ = fmaf(dppmov<RORc(9)>(X),  W[9],  b1_);                       \
    b2_ = fmaf(dppmov<RORc(10)>(X), W[10], b2_);                       \
    b3_ = fmaf(dppmov<RORc(11)>(X), W[11], b3_);                       \
    b4_ = fmaf(dppmov<RORc(12)>(X), W[12], b4_);                       \
    b5_ = fmaf(dppmov<RORc(13)>(X), W[13], b5_);                       \
    b6_ = fmaf(dppmov<RORc(14)>(X), W[14], b6_);                       \
    b7_ = fmaf(dppmov<RORc(15)>(X), W[15], b7_);                       \
    SOUT = ((b0_ + b1_) + (b2_ + b3_)) + ((b4_ + b5_) + (b6_ + b7_));  \
  } while (0)

__global__ __launch_bounds__(512) __attribute__((amdgpu_waves_per_eu(1, 2)))
void ode_kernel(const float* __restrict__ s_grid,
                const float* __restrict__ y0in,
                const float* __restrict__ Win,
                const float* __restrict__ bin_,
                const float* __restrict__ W1a, const float* __restrict__ b1a,
                const float* __restrict__ W1b, const float* __restrict__ b1b,
                const float* __restrict__ W2a, const float* __restrict__ b2a,
                const float* __restrict__ W2b, const float* __restrict__ b2b,
                const float* __restrict__ Wout, const float* __restrict__ bout,
                const float* __restrict__ Aarr,
                float* __restrict__ out, int T) {
  const int tid = threadIdx.x;
  const int wv = tid >> 6;        // 0..7
  const int role = wv >> 2;       // 0 = correction(step t), 1 = prediction(t+1)
  const int st = wv & 3;          // RK stage owned
  const int lane = tid & 63;
  const int i = lane & 15;
  const int m = lane >> 4;
  const int mlo = m & 1;
  const int mhi = m >> 1;

  // ---- LDS: s_grid + double-buffered exchange [buf][slot][lane] ----
  // slots 0-3: corrected C stages; 4-7: predicted P stages
  __shared__ float s_lds[4096];
  __shared__ float Xg[2][8][64], Xa[2][8][64], Xb[2][8][64];
  for (int idx = tid; idx < T && idx < 4096; idx += 512)
    s_lds[idx] = s_grid[idx];
  __syncthreads();

  // ---- direction probes ----
  int delta;
  {
    float pr = (float)i;
    float pr1 = dppmov<RORc(1)>(pr);
    delta = (((int)pr1) - i) & 15;
  }
  bool p32_c_low;
  {
    float v = (float)(lane >> 5);
    float c = v, d = v;
    p32swap(c, d);
    p32_c_low = (c == 0.0f);
  }

  // ---- weight prep (one-time, identical to r7-r11; per-lane) ----
  const int rA = 16 * mhi + i, hA = mlo;
  const int rB = 16 * mlo + i, hB = mhi;
  const int r_in = 16 * mlo + i;
  const int e1 = r_in;

  float w1a[16], w2a[16], m21[16];
#pragma unroll 1
  for (int k = 0; k < 16; ++k) {
    int cA = hA * 16 + ((i + delta * k) & 15);
    int cB = hB * 16 + ((i + delta * k) & 15);
    w1a[k] = W1a[rA * 32 + cA] * (-2.0f * C_TANH);
    w2a[k] = W2a[rA * 32 + cA] * (-2.0f * C_TANH);
    float acc = 0.0f;
    for (int q = 0; q < 32; ++q)
      acc = fmaf(W2a[rB * 32 + q], W1b[q * 32 + cB], acc);
    m21[k] = acc * (-2.0f * C_TANH);
  }
  float bz1a;
  {
    float rs = 0.0f;
    for (int c = 0; c < 32; ++c) rs += W1a[rA * 32 + c];
    bz1a = hA ? 0.0f : C_TANH * (b1a[rA] + rs);
  }
  float c2sel;
  {
    float rs2a = 0.0f, m21rs = 0.0f, wb = 0.0f;
    for (int q = 0; q < 32; ++q) {
      float w2q = W2a[rB * 32 + q];
      rs2a += w2q;
      float rs1bq = 0.0f;
      for (int c = 0; c < 32; ++c) rs1bq += W1b[q * 32 + c];
      m21rs = fmaf(w2q, rs1bq, m21rs);
      wb = fmaf(w2q, b1b[q], wb);
    }
    c2sel = hB ? 0.0f : C_TANH * (rs2a + m21rs + wb + b2a[rB]);
  }
  const bool seedsel = (mlo == mhi);

  float winy0 = Win[r_in * 5 + 0] * C_TANH;
  float winy1 = Win[r_in * 5 + 1] * C_TANH;
  float winy2 = Win[r_in * 5 + 2] * C_TANH;
  float winy3 = Win[r_in * 5 + 3] * C_TANH;
  float wins  = Win[r_in * 5 + 4] * C_TANH;
  float binr  = bin_[r_in] * C_TANH;
  float gsel_a = mhi ? winy2 : winy0;
  float gsel_b = mhi ? winy3 : winy1;

  const int ra_ = 2 * mhi, rb_ = 2 * mhi + 1;
  float woXa = Wout[ra_ * 32 + e1] * (-2.0f * C_NSIG);
  float woXb = Wout[rb_ * 32 + e1] * (-2.0f * C_NSIG);
  float wo1a, wo1b, wo2a, wo2b, boa, bob;
  {
    float w1s_a = 0.0f, w1s_b = 0.0f, w2s_a = 0.0f, w2s_b = 0.0f;
    float rsX_a = 0.0f, rsX_b = 0.0f, rs1_a = 0.0f, rs1_b = 0.0f;
    float rs2_a = 0.0f, rs2_b = 0.0f, bt_a = 0.0f, bt_b = 0.0f;
    for (int q = 0; q < 32; ++q) {
      float waq = Wout[ra_ * 32 + q], wbq = Wout[rb_ * 32 + q];
      w1s_a = fmaf(waq, W1b[q * 32 + e1], w1s_a);
      w1s_b = fmaf(wbq, W1b[q * 32 + e1], w1s_b);
      w2s_a = fmaf(waq, W2b[q * 32 + e1], w2s_a);
      w2s_b = fmaf(wbq, W2b[q * 32 + e1], w2s_b);
      rsX_a += waq; rsX_b += wbq;
      float rs1bq = 0.0f, rs2bq = 0.0f;
      for (int c = 0; c < 32; ++c) {
        rs1bq += W1b[q * 32 + c];
        rs2bq += W2b[q * 32 + c];
      }
      rs1_a = fmaf(waq, rs1bq, rs1_a); rs1_b = fmaf(wbq, rs1bq, rs1_b);
      rs2_a = fmaf(waq, rs2bq, rs2_a); rs2_b = fmaf(wbq, rs2bq, rs2_b);
      float bs = b1b[q] + b2b[q];
      bt_a = fmaf(waq, bs, bt_a); bt_b = fmaf(wbq, bs, bt_b);
    }
    wo1a = w1s_a * (-2.0f * C_NSIG); wo1b = w1s_b * (-2.0f * C_NSIG);
    wo2a = w2s_a * (-2.0f * C_NSIG); wo2b = w2s_b * (-2.0f * C_NSIG);
    boa = (bout[ra_] + bt_a + rsX_a + rs1_a + rs2_a) * (C_NSIG / 32.0f);
    bob = (bout[rb_] + bt_b + rsX_b + rs1_b + rs2_b) * (C_NSIG / 32.0f);
  }
  float Aa = mhi ? Aarr[2] : Aarr[0];
  float Ab = mhi ? Aarr[3] : Aarr[1];

  auto relayout = [&](float v) -> float {
    float c = v, d = v;
    p32swap(c, d);
    float lo = p32_c_low ? c : d;
    float hi = p32_c_low ? d : c;
    return mlo ? hi : lo;
  };

  float pfa, pfb, wpa, wpb, na, nb, gkv;

  auto setpref = [&](float yA, float yB) {
    float sa = frcp(1.0f + fexp2(yA * C_NSIG));
    float sb = frcp(1.0f + fexp2(yB * C_NSIG));
    pfa = 0.01f * sa * (Aa - sa);
    pfb = 0.01f * sb * (Ab - sb);
    wpa = gsel_a * pfa;
    wpb = gsel_b * pfb;
  };

  auto STAGE = [&](float zin) {
    float g0v = frcp(fexp2(zin) + 1.0f);                   // ABAB
    float u1; MV8(w1a, bz1a, g0v, u1);
    { float b = u1; p16swap(u1, b); u1 += b; }             // AABB
    float q2; MV8(w2a, 0.0f, g0v, q2);
    { float b = q2; p16swap(q2, b); q2 += b; }             // AABB
    float g1 = frcp(fexp2(u1) + 1.0f);
    float g1r = relayout(g1);
    float seed = (seedsel ? q2 : 0.0f) + c2sel;
    float u2; MV8(m21, seed, g1, u2);
    { float b = u2; p32swap(u2, b); u2 += b; }             // ABAB
    float g2 = frcp(fexp2(u2) + 1.0f);
    float ph0 = fmaf(wo1a, g1r, fmaf(woXa, g0v, boa));
    float ph1 = fmaf(wo1b, g1r, fmaf(woXb, g0v, bob));
    float p0 = fmaf(wo2a, g2, ph0);
    float p1 = fmaf(wo2b, g2, ph1);
    p0 += dppmov<RORc(8)>(p0); p1 += dppmov<RORc(8)>(p1);
    p0 += dppmov<RORc(4)>(p0); p1 += dppmov<RORc(4)>(p1);
    p0 += dppmov<RORc(2)>(p0); p1 += dppmov<RORc(2)>(p1);
    p0 += dppmov<RORc(1)>(p0); p1 += dppmov<RORc(1)>(p1);
    { float q = p0; p16swap(p0, q); p0 += q; }
    { float q = p1; p16swap(p1, q); p1 += q; }
    na = frcp(1.0f + fexp2(p0));
    nb = frcp(1.0f + fexp2(p1));
    float gp = fmaf(wpb, nb, wpa * na);
    float gq = gp;
    p32swap(gp, gq);
    gkv = gp + gq;
  };

  // ---- state (every wave tracks identically) ----
  float y00 = y0in[0], y01 = y0in[1], y02 = y0in[2], y03 = y0in[3];
  float ya = mhi ? y02 : y00;
  float yb = mhi ? y03 : y01;

  if (wv == 0 && (lane & 0x1E) == 0)
    out[(lane >> 4) + (lane & 1)] = (lane & 1) ? yb : ya;

  float sp = s_lds[0];
  float sn = (T > 1) ? s_lds[1] : sp;

  float zb = fmaf(winy0, y00, fmaf(winy1, y01, fmaf(winy2, y02,
             fmaf(winy3, y03, fmaf(wins, sp, binr)))));

  // ---- prologue: prediction waves predict step 0 (exact y0, zero
  //      stage-input guesses -> stage 0 = exact k1, as in r8 iter1) ----
  if (role == 1) {
    setpref(ya, yb);
    STAGE(zb);
    float Ka = pfa * na, Kb = pfb * nb;
    Xg[0][4 + st][lane] = gkv;
    Xa[0][4 + st][lane] = Ka;
    Xb[0][4 + st][lane] = Kb;
  }
  __syncthreads();

  float h6p = 0.0f, zbwp = 0.0f;

  for (int t = 0; t < T - 1; ++t) {
    const int p = t & 1, q = p ^ 1;
    const int i2 = (t + 2 < T) ? (t + 2) : (T - 1);
    float snn = s_lds[i2];

    // ---- read phase (all from buf p; written iter t-1 / prologue) ----
    float Pg[4], Pa[4], Pb[4];
#pragma unroll
    for (int j = 0; j < 4; ++j) {
      Pg[j] = Xg[p][4 + j][lane];
      Pa[j] = Xa[p][4 + j][lane];
      Pb[j] = Xb[p][4 + j][lane];
    }
    if (t) {  // finalize y(t), zb(t) from corrected C(t-1)
      float Cg0 = Xg[p][0][lane], Cg1 = Xg[p][1][lane];
      float Cg2 = Xg[p][2][lane], Cg3 = Xg[p][3][lane];
      float Ca0 = Xa[p][0][lane], Ca1 = Xa[p][1][lane];
      float Ca2 = Xa[p][2][lane], Ca3 = Xa[p][3][lane];
      float Cb0 = Xb[p][0][lane], Cb1 = Xb[p][1][lane];
      float Cb2 = Xb[p][2][lane], Cb3 = Xb[p][3][lane];
      float agC = Cg0 + Cg3 + 2.0f * (Cg1 + Cg2);
      float aaC = Ca0 + Ca3 + 2.0f * (Ca1 + Ca2);
      float abC = Cb0 + Cb3 + 2.0f * (Cb1 + Cb2);
      ya = fmaf(h6p, aaC, ya);
      yb = fmaf(h6p, abC, yb);
      zb = fmaf(h6p, agC, zbwp);
      if (wv == 0 && (lane & 0x1E) == 0)
        out[(size_t)t * 4 + (lane >> 4) + (lane & 1)] = (lane & 1) ? yb : ya;
    }

    float h = sn - sp;
    float hh = 0.5f * h;
    float h6 = h * (1.0f / 6.0f);
    float zbw = fmaf(wins, h, zb);
    float hn = snn - sn;

    // ---- eval (correction of t OR prediction of t+1; same input idiom) ----
    float agP = Pg[0] + Pg[3] + 2.0f * (Pg[1] + Pg[2]);
    float aaP = Pa[0] + Pa[3] + 2.0f * (Pa[1] + Pa[2]);
    float abP = Pb[0] + Pb[3] + 2.0f * (Pb[1] + Pb[2]);
    float yga = fmaf(h6, aaP, ya);
    float ygb = fmaf(h6, abP, yb);
    float zbg = fmaf(h6, agP, zbw);

    float cwC = (st == 0) ? 0.0f : (st == 3) ? h  : hh;
    float cwP = (st == 0) ? 0.0f : (st == 3) ? hn : 0.5f * hn;
    float cwE = role ? cwP : cwC;
    float yA0 = role ? yga : ya;
    float yB0 = role ? ygb : yb;
    float zB0 = role ? zbg : zb;
    float gin  = st ? Pg[st - 1] : 0.0f;
    float kain = st ? Pa[st - 1] : 0.0f;
    float kbin = st ? Pb[st - 1] : 0.0f;

    setpref(fmaf(cwE, kain, yA0), fmaf(cwE, kbin, yB0));
    STAGE(fmaf(cwE, gin, zB0));
    float Ka = pfa * na, Kb = pfb * nb;

    const int slot = role * 4 + st;
    Xg[q][slot][lane] = gkv;
    Xa[q][slot][lane] = Ka;
    Xb[q][slot][lane] = Kb;

    h6p = h6;
    zbwp = zbw;
    __syncthreads();

    sp = sn;
    sn = snn;
  }

  // ---- epilogue: finalize y(T-1) from C(T-2) ----
  {
    const int p = (T - 1) & 1;
    float Cg0 = Xg[p][0][lane], Cg1 = Xg[p][1][lane];
    float Cg2 = Xg[p][2][lane], Cg3 = Xg[p][3][lane];
    float Ca0 = Xa[p][0][lane], Ca1 = Xa[p][1][lane];
    float Ca2 = Xa[p][2][lane], Ca3 = Xa[p][3][lane];
    float Cb0 = Xb[p][0][lane], Cb1 = Xb[p][1][lane];
    float Cb2 = Xb[p][2][lane], Cb3 = Xb[p][3][lane];
    (void)Cg0; (void)Cg1; (void)Cg2; (void)Cg3;
    float aaC = Ca0 + Ca3 + 2.0f * (Ca1 + Ca2);
    float abC = Cb0 + Cb3 + 2.0f * (Cb1 + Cb2);
    ya = fmaf(h6p, aaC, ya);
    yb = fmaf(h6p, abC, yb);
    if (wv == 0 && (lane & 0x1E) == 0)
      out[(size_t)(T - 1) * 4 + (lane >> 4) + (lane & 1)] = (lane & 1) ? yb : ya;
  }
}

extern "C" void kernel_launch(void* const* d_in, const int* in_sizes, int n_in,
                              void* d_out, int out_size, void* d_ws, size_t ws_size,
                              hipStream_t stream) {
  const float* s_grid = (const float*)d_in[0];
  const float* y0 = (const float*)d_in[1];
  const float* Win = (const float*)d_in[2];
  const float* bin_ = (const float*)d_in[3];
  const float* W1a = (const float*)d_in[4];
  const float* b1a = (const float*)d_in[5];
  const float* W1b = (const float*)d_in[6];
  const float* b1b = (const float*)d_in[7];
  const float* W2a = (const float*)d_in[8];
  const float* b2a = (const float*)d_in[9];
  const float* W2b = (const float*)d_in[10];
  const float* b2b = (const float*)d_in[11];
  const float* Wout = (const float*)d_in[12];
  const float* bout = (const float*)d_in[13];
  const float* A = (const float*)d_in[14];
  int T = in_sizes[0];

  ode_kernel<<<1, 512, 0, stream>>>(s_grid, y0, Win, bin_, W1a, b1a, W1b, b1b,
                                    W2a, b2a, W2b, b2b, Wout, bout, A,
                                    (float*)d_out, T);
}